// Round 2
// baseline (5754.787 us; speedup 1.0000x reference)
//
#include <hip/hip_runtime.h>
#include <cfloat>

// Problem constants
#define B_SZ 32768
#define K_SZ 8192
#define D_SZ 512

static constexpr float DECAY = 0.99f;
static constexpr float OMD   = 1.0f - 0.99f;   // (1 - decay) in fp32
static constexpr float EPS   = 1e-5f;

// ---------------------------------------------------------------------------
// Kernel A: row sum-of-squares. One wave per row (D=512). Used for both
// c_sq (codebook rows) and z_sq (z_e rows); results parked in o_zq scratch.
// ---------------------------------------------------------------------------
__global__ __launch_bounds__(256)
void rowsq_kernel(const float* __restrict__ src, float* __restrict__ dst) {
    const int wave = threadIdx.x >> 6;
    const int lane = threadIdx.x & 63;
    const int r = blockIdx.x * 4 + wave;
    const float* row = src + (size_t)r * D_SZ;
    float s = 0.f;
#pragma unroll
    for (int i = 0; i < 2; ++i) {
        float4 v = *reinterpret_cast<const float4*>(row + i * 256 + lane * 4);
        s += v.x * v.x + v.y * v.y + v.z * v.z + v.w * v.w;
    }
#pragma unroll
    for (int off = 32; off >= 1; off >>= 1) s += __shfl_xor(s, off);
    if (lane == 0) dst[r] = s;
}

// ---------------------------------------------------------------------------
// Kernel B: EMA init. o_nemcb = DECAY*ema_cb; o_ncs = DECAY*ema_cs.
// Scatter kernel later accumulates the (1-decay)*segment_sum terms on top.
// ---------------------------------------------------------------------------
__global__ __launch_bounds__(256)
void init_ema_kernel(const float* __restrict__ ema_cb,
                     const float* __restrict__ ema_cs,
                     float* __restrict__ o_nemcb,
                     float* __restrict__ o_ncs) {
    const size_t i = (size_t)blockIdx.x * 256 + threadIdx.x;  // float4 index
    float4 e = *reinterpret_cast<const float4*>(ema_cb + i * 4);
    e.x *= DECAY; e.y *= DECAY; e.z *= DECAY; e.w *= DECAY;
    *reinterpret_cast<float4*>(o_nemcb + i * 4) = e;
    if (i < K_SZ) o_ncs[i] = DECAY * ema_cs[i];
}

// ---------------------------------------------------------------------------
// Kernel 1: fused distance argmin.
// Block: 256 threads, handles 32 rows of z_e against all K codes.
// d2(b,k) = (z_sq[b] - 2*dot) + c_sq[k]  -- op order matches numpy exactly
// (2*acc is exact, fmaf(-2,acc,z_sq) == round(z_sq - round(2*acc))).
// LDS: zs[32][512] staged once (64 KB); cs[32][128] d-major per k-tile/d-chunk.
// Micro-tile 4 rows x 4 cols per thread; rg = tid>>5, cg = tid&31.
// ---------------------------------------------------------------------------
__global__ __launch_bounds__(256, 2)
void argmin_kernel(const float* __restrict__ z_e,
                   const float* __restrict__ codebook,
                   const float* __restrict__ c_sq,
                   const float* __restrict__ z_sq,
                   float* __restrict__ out_idx_f)  // B floats
{
    __shared__ float zs[32 * 512];   // 64 KB
    __shared__ float cs[32 * 128];   // 16 KB (d-major: cs[d][n])

    const int tid = threadIdx.x;
    const int cg  = tid & 31;        // col group: cols cg*4 .. cg*4+3 (of 128)
    const int rg  = tid >> 5;        // row group: rows rg*4 .. rg*4+3 (of 32)
    const int b0  = blockIdx.x * 32;

    // Stage z tile: 32x512 floats = 4096 float4, 16 per thread. Coalesced.
#pragma unroll
    for (int i = 0; i < 16; ++i) {
        int lin = i * 256 + tid;       // float4 index 0..4095
        int r   = lin >> 7;            // 0..31
        int d4  = lin & 127;           // 0..127
        float4 v = *reinterpret_cast<const float4*>(
            z_e + (size_t)(b0 + r) * D_SZ + d4 * 4);
        *reinterpret_cast<float4*>(zs + r * D_SZ + d4 * 4) = v;
    }

    float zsqr[4];
#pragma unroll
    for (int j = 0; j < 4; ++j) zsqr[j] = z_sq[b0 + rg * 4 + j];

    float minv[4];
    int   mini[4];
#pragma unroll
    for (int j = 0; j < 4; ++j) { minv[j] = FLT_MAX; mini[j] = 0; }

    float acc[4][4];

    for (int kt = 0; kt < K_SZ / 128; ++kt) {
        const int k0 = kt * 128;
#pragma unroll
        for (int j = 0; j < 4; ++j)
#pragma unroll
            for (int c = 0; c < 4; ++c) acc[j][c] = 0.f;

        for (int dc = 0; dc < D_SZ; dc += 32) {
            __syncthreads();   // protect cs from previous chunk's readers
            // Stage cs[d][n]: 128 codes x 32 d. 1024 float4 loads, 4/thread.
#pragma unroll
            for (int i = 0; i < 4; ++i) {
                int lin = i * 256 + tid;   // 0..1023
                int dg  = lin & 7;         // 0..7  (d sub-group of 4)
                int n   = lin >> 3;        // 0..127 (code within tile)
                float4 v = *reinterpret_cast<const float4*>(
                    codebook + (size_t)(k0 + n) * D_SZ + dc + dg * 4);
                cs[(dg * 4 + 0) * 128 + n] = v.x;
                cs[(dg * 4 + 1) * 128 + n] = v.y;
                cs[(dg * 4 + 2) * 128 + n] = v.z;
                cs[(dg * 4 + 3) * 128 + n] = v.w;
            }
            __syncthreads();

#pragma unroll
            for (int d4 = 0; d4 < 32; d4 += 4) {
                float av[4][4];
                float4 bb[4];
#pragma unroll
                for (int j = 0; j < 4; ++j) {
                    float4 t = *reinterpret_cast<const float4*>(
                        zs + (rg * 4 + j) * D_SZ + dc + d4);
                    av[j][0] = t.x; av[j][1] = t.y; av[j][2] = t.z; av[j][3] = t.w;
                }
#pragma unroll
                for (int q = 0; q < 4; ++q)
                    bb[q] = *reinterpret_cast<const float4*>(
                        cs + (d4 + q) * 128 + cg * 4);
#pragma unroll
                for (int q = 0; q < 4; ++q) {
#pragma unroll
                    for (int j = 0; j < 4; ++j) {
                        acc[j][0] += av[j][q] * bb[q].x;
                        acc[j][1] += av[j][q] * bb[q].y;
                        acc[j][2] += av[j][q] * bb[q].z;
                        acc[j][3] += av[j][q] * bb[q].w;
                    }
                }
            }
        }

        // Fold this k-tile into the running argmin.
        float4 csq = *reinterpret_cast<const float4*>(c_sq + k0 + cg * 4);
        float csqv[4] = {csq.x, csq.y, csq.z, csq.w};
#pragma unroll
        for (int j = 0; j < 4; ++j) {
#pragma unroll
            for (int c = 0; c < 4; ++c) {
                // (z_sq - 2*acc) + c_sq, numpy's exact elementwise op order
                float t = fmaf(-2.f, acc[j][c], zsqr[j]);
                float s = t + csqv[c];
                int k = k0 + cg * 4 + c;
                // strict < : within a thread k only increases -> first-min kept
                if (s < minv[j]) { minv[j] = s; mini[j] = k; }
            }
        }
    }

    // Cross-thread reduction over cg (32 lanes of each half-wave share rows).
#pragma unroll
    for (int j = 0; j < 4; ++j) {
        float v = minv[j];
        int   idx = mini[j];
#pragma unroll
        for (int off = 16; off >= 1; off >>= 1) {
            float v2 = __shfl_xor(v, off);
            int   i2 = __shfl_xor(idx, off);
            if (v2 < v || (v2 == v && i2 < idx)) { v = v2; idx = i2; }
        }
        if (cg == 0) out_idx_f[b0 + rg * 4 + j] = (float)idx;
    }
}

// ---------------------------------------------------------------------------
// Kernel 2: gather z_q + scatter EMA contributions straight into the outputs:
//   o_nemcb += OMD * z_e[b]   (atomic, per selected code row)
//   o_ncs   += OMD            (atomic, one per row, lane 0)
// One wave per row of z_e.
// ---------------------------------------------------------------------------
__global__ __launch_bounds__(256)
void scatter_kernel(const float* __restrict__ z_e,
                    const float* __restrict__ codebook,
                    const float* __restrict__ out_idx_f,
                    float* __restrict__ z_q,
                    float* __restrict__ o_ncs,
                    float* __restrict__ o_nemcb)
{
    const int wave = threadIdx.x >> 6;
    const int lane = threadIdx.x & 63;
    const int b = blockIdx.x * 4 + wave;
    const int idx = (int)out_idx_f[b];
#pragma unroll
    for (int i = 0; i < 2; ++i) {
        int d = i * 256 + lane * 4;
        float4 cq = *reinterpret_cast<const float4*>(
            codebook + (size_t)idx * D_SZ + d);
        *reinterpret_cast<float4*>(z_q + (size_t)b * D_SZ + d) = cq;
        float4 zv = *reinterpret_cast<const float4*>(
            z_e + (size_t)b * D_SZ + d);
        atomicAdd(o_nemcb + (size_t)idx * D_SZ + d + 0, OMD * zv.x);
        atomicAdd(o_nemcb + (size_t)idx * D_SZ + d + 1, OMD * zv.y);
        atomicAdd(o_nemcb + (size_t)idx * D_SZ + d + 2, OMD * zv.z);
        atomicAdd(o_nemcb + (size_t)idx * D_SZ + d + 3, OMD * zv.w);
    }
    if (lane == 0) atomicAdd(o_ncs + idx, OMD);
}

// ---------------------------------------------------------------------------
// Kernel 3: new_codebook = new_ema_codebook / (new_cluster_size + EPS).
// One thread per float4 of (K, D). Reads the already-final output buffers.
// ---------------------------------------------------------------------------
__global__ __launch_bounds__(256)
void finalize_kernel(const float* __restrict__ o_nemcb,
                     const float* __restrict__ o_ncs,
                     float* __restrict__ o_ncb)
{
    const size_t i = (size_t)blockIdx.x * 256 + threadIdx.x;  // float4 index
    const int k = (int)(i >> 7);                   // 128 float4 per row
    float4 nem = *reinterpret_cast<const float4*>(o_nemcb + i * 4);
    float den = o_ncs[k] + EPS;
    float4 ncb;
    ncb.x = nem.x / den; ncb.y = nem.y / den;
    ncb.z = nem.z / den; ncb.w = nem.w / den;
    *reinterpret_cast<float4*>(o_ncb + i * 4) = ncb;
}

// ---------------------------------------------------------------------------
extern "C" void kernel_launch(void* const* d_in, const int* in_sizes, int n_in,
                              void* d_out, int out_size, void* d_ws, size_t ws_size,
                              hipStream_t stream) {
    const float* z_e      = (const float*)d_in[0];   // (B, D)
    const float* codebook = (const float*)d_in[1];   // (K, D)
    const float* ema_cs   = (const float*)d_in[2];   // (K,)
    const float* ema_cb   = (const float*)d_in[3];   // (K, D)

    float* out = (float*)d_out;
    // Output layout (flat, return order):
    float* o_zq    = out;                                  // B*D
    float* o_idx   = out + (size_t)B_SZ * D_SZ;            // B
    float* o_ncb   = o_idx + B_SZ;                         // K*D
    float* o_ncs   = o_ncb + (size_t)K_SZ * D_SZ;          // K
    float* o_nemcb = o_ncs + K_SZ;                         // K*D

    // Scratch parked inside o_zq (overwritten by scatter_kernel at the end):
    //   c_sq[K] at o_zq[0:8192], z_sq[B] at o_zq[8192:40960].
    // ZERO d_ws usage -> immune to any ws_size assumption.
    float* w_csq = o_zq;
    float* w_zsq = o_zq + K_SZ;

    rowsq_kernel<<<K_SZ / 4, 256, 0, stream>>>(codebook, w_csq);
    rowsq_kernel<<<B_SZ / 4, 256, 0, stream>>>(z_e, w_zsq);
    init_ema_kernel<<<K_SZ * D_SZ / 4 / 256, 256, 0, stream>>>(
        ema_cb, ema_cs, o_nemcb, o_ncs);
    argmin_kernel<<<B_SZ / 32, 256, 0, stream>>>(z_e, codebook,
                                                 w_csq, w_zsq, o_idx);
    scatter_kernel<<<B_SZ / 4, 256, 0, stream>>>(z_e, codebook, o_idx,
                                                 o_zq, o_ncs, o_nemcb);
    finalize_kernel<<<K_SZ * D_SZ / 4 / 256, 256, 0, stream>>>(
        o_nemcb, o_ncs, o_ncb);
}

// Round 3
// 3309.783 us; speedup vs baseline: 1.7387x; 1.7387x over previous
//
#include <hip/hip_runtime.h>
#include <cfloat>

// Problem constants
#define B_SZ 32768
#define K_SZ 8192
#define D_SZ 512

static constexpr float DECAY = 0.99f;
static constexpr float OMD   = 1.0f - 0.99f;   // (1 - decay) in fp32
static constexpr float EPS   = 1e-5f;

// ---------------------------------------------------------------------------
// Kernel A: row sum-of-squares. One wave per row (D=512). Results parked in
// o_zq scratch (overwritten by scatter_kernel at the end of the stream).
// ---------------------------------------------------------------------------
__global__ __launch_bounds__(256)
void rowsq_kernel(const float* __restrict__ src, float* __restrict__ dst) {
    const int wave = threadIdx.x >> 6;
    const int lane = threadIdx.x & 63;
    const int r = blockIdx.x * 4 + wave;
    const float* row = src + (size_t)r * D_SZ;
    float s = 0.f;
#pragma unroll
    for (int i = 0; i < 2; ++i) {
        float4 v = *reinterpret_cast<const float4*>(row + i * 256 + lane * 4);
        s += v.x * v.x + v.y * v.y + v.z * v.z + v.w * v.w;
    }
#pragma unroll
    for (int off = 32; off >= 1; off >>= 1) s += __shfl_xor(s, off);
    if (lane == 0) dst[r] = s;
}

// ---------------------------------------------------------------------------
// Kernel B: EMA init. o_nemcb = DECAY*ema_cb; o_ncs = DECAY*ema_cs.
// ---------------------------------------------------------------------------
__global__ __launch_bounds__(256)
void init_ema_kernel(const float* __restrict__ ema_cb,
                     const float* __restrict__ ema_cs,
                     float* __restrict__ o_nemcb,
                     float* __restrict__ o_ncs) {
    const size_t i = (size_t)blockIdx.x * 256 + threadIdx.x;  // float4 index
    float4 e = *reinterpret_cast<const float4*>(ema_cb + i * 4);
    e.x *= DECAY; e.y *= DECAY; e.z *= DECAY; e.w *= DECAY;
    *reinterpret_cast<float4*>(o_nemcb + i * 4) = e;
    if (i < K_SZ) o_ncs[i] = DECAY * ema_cs[i];
}

// ---------------------------------------------------------------------------
// Kernel 1: distance argmin, restructured.
// Grid: 256 row-blocks x 64 col-blocks (cb = blockIdx.x & 63 fast).
// Block: 256 threads = 4 waves; tile 128 rows x 128 cols; thread-tile 8x8.
//   tr = lane&15  -> rows tr*8..+7 (same for all waves)
//   col = wid*32 + (lane>>4)*8 .. +7
// LDS: zst[32][128], cst[32][128] d-major, XOR-swizzled (p = r ^ SW(d),
//   SW(d) = ((d>>2)&3)<<3). Staging transpose-writes: 2-way conflicts (free).
//   a-reads: 4-phase BW floor. b-reads: 16-lane broadcast (free).
// d2 = fmaf(-2, dot, z_sq) + c_sq  -- same op order + same sequential-d
// accumulation order as the passing R1 kernel -> bit-identical scores.
// Output: per-block per-row (min,idx) partials[row][cb] (float2).
// ---------------------------------------------------------------------------
#define SW(d) ((((d) >> 2) & 3) << 3)

__global__ __launch_bounds__(256, 4)
void argmin_kernel(const float* __restrict__ z_e,
                   const float* __restrict__ codebook,
                   const float* __restrict__ c_sq,
                   const float* __restrict__ z_sq,
                   float2* __restrict__ partials)   // [B][64]
{
    __shared__ float zst[32][128];       // 16 KB  [d][r^SW(d)]
    __shared__ float cst[32][128];       // 16 KB  [d][n^SW(d)]
    __shared__ float mbuf[4][128][2];    // 4 KB   cross-wave argmin merge

    const int tid  = threadIdx.x;
    const int wid  = tid >> 6;
    const int lane = tid & 63;
    const int tr   = lane & 15;          // row group
    const int tr8  = tr * 8;
    const int c0l  = wid * 32 + (lane >> 4) * 8;   // local col base (0..120)

    const int rb = blockIdx.x >> 6;      // row block 0..255
    const int cb = blockIdx.x & 63;      // col block 0..63
    const int b0 = rb * 128;
    const int k0 = cb * 128;

    float acc[8][8];
#pragma unroll
    for (int r = 0; r < 8; ++r)
#pragma unroll
        for (int c = 0; c < 8; ++c) acc[r][c] = 0.f;

    for (int dc = 0; dc < D_SZ; dc += 32) {
        __syncthreads();   // previous chunk's readers done
        // Stage 128x32 of z and codebook, transposed to d-major w/ swizzle.
        // lin: d4 = lin&7 (float4 within the 32-d chunk), n = lin>>3 (row).
        // Global: 8 lanes x 16 B = 128 B contiguous per row -> coalesced.
        // LDS writes: bank = (n ^ 8*(d4&3)) & 31 -> 32 banks, 2 lanes each
        // at different addresses = 2-way = free (m136).
#pragma unroll
        for (int it = 0; it < 4; ++it) {
            int lin = it * 256 + tid;
            int d4  = lin & 7;
            int n   = lin >> 3;
            int p   = n ^ ((d4 & 3) << 3);   // SW(d4*4+j) == 8*(d4&3) for j<4
            float4 vz = *reinterpret_cast<const float4*>(
                z_e + (size_t)(b0 + n) * D_SZ + dc + d4 * 4);
            float4 vc = *reinterpret_cast<const float4*>(
                codebook + (size_t)(k0 + n) * D_SZ + dc + d4 * 4);
            zst[d4 * 4 + 0][p] = vz.x;  cst[d4 * 4 + 0][p] = vc.x;
            zst[d4 * 4 + 1][p] = vz.y;  cst[d4 * 4 + 1][p] = vc.y;
            zst[d4 * 4 + 2][p] = vz.z;  cst[d4 * 4 + 2][p] = vc.z;
            zst[d4 * 4 + 3][p] = vz.w;  cst[d4 * 4 + 3][p] = vc.w;
        }
        __syncthreads();

#pragma unroll 4
        for (int d = 0; d < 32; ++d) {
            const int sw = SW(d);
            // physical run (x^sw)+i == logical (x+i)^sw for i<8, sw mult of 8
            float4 a0 = *reinterpret_cast<const float4*>(&zst[d][tr8 ^ sw]);
            float4 a1 = *reinterpret_cast<const float4*>(&zst[d][(tr8 + 4) ^ sw]);
            float4 bb0 = *reinterpret_cast<const float4*>(&cst[d][c0l ^ sw]);
            float4 bb1 = *reinterpret_cast<const float4*>(&cst[d][(c0l + 4) ^ sw]);
            float av[8] = {a0.x, a0.y, a0.z, a0.w, a1.x, a1.y, a1.z, a1.w};
            float bv[8] = {bb0.x, bb0.y, bb0.z, bb0.w, bb1.x, bb1.y, bb1.z, bb1.w};
#pragma unroll
            for (int r = 0; r < 8; ++r)
#pragma unroll
                for (int c = 0; c < 8; ++c)
                    acc[r][c] = fmaf(av[r], bv[c], acc[r][c]);
        }
    }

    // ---- Epilogue: d2 + per-row argmin over this block's 128 cols ----
    float zq[8], cq[8];
#pragma unroll
    for (int j = 0; j < 8; ++j) zq[j] = z_sq[b0 + tr8 + j];
#pragma unroll
    for (int j = 0; j < 8; ++j) cq[j] = c_sq[k0 + c0l + j];

    float mv[8];
    int   mi[8];
#pragma unroll
    for (int r = 0; r < 8; ++r) {
        mv[r] = FLT_MAX; mi[r] = 0;
#pragma unroll
        for (int c = 0; c < 8; ++c) {
            float s = fmaf(-2.f, acc[r][c], zq[r]) + cq[c];
            if (s < mv[r]) { mv[r] = s; mi[r] = k0 + c0l + c; }
        }
        // merge across the 4 col-groups of this wave (lanes tr, tr+16, +32, +48)
#pragma unroll
        for (int off = 16; off <= 32; off <<= 1) {
            float v2 = __shfl_xor(mv[r], off);
            int   i2 = __shfl_xor(mi[r], off);
            if (v2 < mv[r] || (v2 == mv[r] && i2 < mi[r])) { mv[r] = v2; mi[r] = i2; }
        }
    }
    if ((lane >> 4) == 0) {
#pragma unroll
        for (int r = 0; r < 8; ++r) {
            mbuf[wid][tr8 + r][0] = mv[r];
            mbuf[wid][tr8 + r][1] = (float)mi[r];
        }
    }
    __syncthreads();
    // merge the 4 waves (ascending wid = ascending col -> first-min semantics)
    if (tid < 128) {
        float v = mbuf[0][tid][0];
        int   idx = (int)mbuf[0][tid][1];
#pragma unroll
        for (int w = 1; w < 4; ++w) {
            float v2 = mbuf[w][tid][0];
            int   i2 = (int)mbuf[w][tid][1];
            if (v2 < v || (v2 == v && i2 < idx)) { v = v2; idx = i2; }
        }
        partials[(size_t)(b0 + tid) * 64 + cb] = make_float2(v, (float)idx);
    }
}

// ---------------------------------------------------------------------------
// Kernel 1b: reduce 64 col-block partials per row -> final index.
// One wave per row; tie-break by smaller k (numpy first-min).
// ---------------------------------------------------------------------------
__global__ __launch_bounds__(256)
void reduce_kernel(const float2* __restrict__ partials,
                   float* __restrict__ out_idx_f) {
    const int row  = blockIdx.x * 4 + (threadIdx.x >> 6);
    const int lane = threadIdx.x & 63;
    float2 p = partials[(size_t)row * 64 + lane];
    float v = p.x;
    int idx = (int)p.y;
#pragma unroll
    for (int off = 32; off >= 1; off >>= 1) {
        float v2 = __shfl_xor(v, off);
        int   i2 = __shfl_xor(idx, off);
        if (v2 < v || (v2 == v && i2 < idx)) { v = v2; idx = i2; }
    }
    if (lane == 0) out_idx_f[row] = (float)idx;
}

// ---------------------------------------------------------------------------
// Kernel 2: gather z_q + scatter EMA contributions into the outputs:
//   o_nemcb += OMD * z_e[b] (atomic); o_ncs += OMD (atomic, lane 0).
// ---------------------------------------------------------------------------
__global__ __launch_bounds__(256)
void scatter_kernel(const float* __restrict__ z_e,
                    const float* __restrict__ codebook,
                    const float* __restrict__ out_idx_f,
                    float* __restrict__ z_q,
                    float* __restrict__ o_ncs,
                    float* __restrict__ o_nemcb)
{
    const int wave = threadIdx.x >> 6;
    const int lane = threadIdx.x & 63;
    const int b = blockIdx.x * 4 + wave;
    const int idx = (int)out_idx_f[b];
#pragma unroll
    for (int i = 0; i < 2; ++i) {
        int d = i * 256 + lane * 4;
        float4 cq = *reinterpret_cast<const float4*>(
            codebook + (size_t)idx * D_SZ + d);
        *reinterpret_cast<float4*>(z_q + (size_t)b * D_SZ + d) = cq;
        float4 zv = *reinterpret_cast<const float4*>(
            z_e + (size_t)b * D_SZ + d);
        atomicAdd(o_nemcb + (size_t)idx * D_SZ + d + 0, OMD * zv.x);
        atomicAdd(o_nemcb + (size_t)idx * D_SZ + d + 1, OMD * zv.y);
        atomicAdd(o_nemcb + (size_t)idx * D_SZ + d + 2, OMD * zv.z);
        atomicAdd(o_nemcb + (size_t)idx * D_SZ + d + 3, OMD * zv.w);
    }
    if (lane == 0) atomicAdd(o_ncs + idx, OMD);
}

// ---------------------------------------------------------------------------
// Kernel 3: new_codebook = new_ema_codebook / (new_cluster_size + EPS).
// ---------------------------------------------------------------------------
__global__ __launch_bounds__(256)
void finalize_kernel(const float* __restrict__ o_nemcb,
                     const float* __restrict__ o_ncs,
                     float* __restrict__ o_ncb)
{
    const size_t i = (size_t)blockIdx.x * 256 + threadIdx.x;  // float4 index
    const int k = (int)(i >> 7);
    float4 nem = *reinterpret_cast<const float4*>(o_nemcb + i * 4);
    float den = o_ncs[k] + EPS;
    float4 ncb;
    ncb.x = nem.x / den; ncb.y = nem.y / den;
    ncb.z = nem.z / den; ncb.w = nem.w / den;
    *reinterpret_cast<float4*>(o_ncb + i * 4) = ncb;
}

// ---------------------------------------------------------------------------
extern "C" void kernel_launch(void* const* d_in, const int* in_sizes, int n_in,
                              void* d_out, int out_size, void* d_ws, size_t ws_size,
                              hipStream_t stream) {
    const float* z_e      = (const float*)d_in[0];   // (B, D)
    const float* codebook = (const float*)d_in[1];   // (K, D)
    const float* ema_cs   = (const float*)d_in[2];   // (K,)
    const float* ema_cb   = (const float*)d_in[3];   // (K, D)

    float* out = (float*)d_out;
    float* o_zq    = out;                                  // B*D
    float* o_idx   = out + (size_t)B_SZ * D_SZ;            // B
    float* o_ncb   = o_idx + B_SZ;                         // K*D
    float* o_ncs   = o_ncb + (size_t)K_SZ * D_SZ;          // K
    float* o_nemcb = o_ncs + K_SZ;                         // K*D

    // Scratch parked inside o_zq (16.78M floats; scatter_kernel overwrites
    // all of it afterwards). ZERO d_ws usage.
    //   partials: B*64 float2 = 4,194,304 floats
    //   c_sq[K], z_sq[B] after it.
    float2* w_part = (float2*)o_zq;
    float*  w_csq  = o_zq + (size_t)B_SZ * 64 * 2;
    float*  w_zsq  = w_csq + K_SZ;

    rowsq_kernel<<<K_SZ / 4, 256, 0, stream>>>(codebook, w_csq);
    rowsq_kernel<<<B_SZ / 4, 256, 0, stream>>>(z_e, w_zsq);
    init_ema_kernel<<<K_SZ * D_SZ / 4 / 256, 256, 0, stream>>>(
        ema_cb, ema_cs, o_nemcb, o_ncs);
    argmin_kernel<<<(B_SZ / 128) * (K_SZ / 128), 256, 0, stream>>>(
        z_e, codebook, w_csq, w_zsq, w_part);
    reduce_kernel<<<B_SZ / 4, 256, 0, stream>>>(w_part, o_idx);
    scatter_kernel<<<B_SZ / 4, 256, 0, stream>>>(z_e, codebook, o_idx,
                                                 o_zq, o_ncs, o_nemcb);
    finalize_kernel<<<K_SZ * D_SZ / 4 / 256, 256, 0, stream>>>(
        o_nemcb, o_ncs, o_ncb);
}